// Round 3
// baseline (202.335 us; speedup 1.0000x reference)
//
#include <hip/hip_runtime.h>
#include <hip/hip_bf16.h>

// IcosahedronConv2d: out[b,v,o] = sum_{k,c} x[b, idx[v,k], c] * mask[v,k] * w[o,c,k] + bias[o]
// B=8, V=10242, C=128, 9 k-slots (7,8 always masked; 6 masked only for 12 pentagons).
// v3: xb bf16 prepass + zero-page gather, B-direct-from-global (no Bs LDS),
//     single 32KB A-tile + register-prefetch pipeline (T14), full-grid residency.

#define V_CNT    10242
#define CC       128
#define KS_ACT   7
#define BM       128
#define VT_PER_B 81          // ceil(10242/128)
#define BATCH    8

typedef short short8 __attribute__((ext_vector_type(8)));
typedef float f32x4  __attribute__((ext_vector_type(4)));

__device__ __forceinline__ unsigned f2bf(float f) {
    unsigned u = __float_as_uint(f);
    u += 0x7fffu + ((u >> 16) & 1u);      // RNE
    return u >> 16;
}

// ws layout (bytes):
//   xb : [0, 20975616)            8*10242*128 bf16
//   wb : [20975616, 21204992)     7*128*128 bf16   Wb[k][o][c]
//   zp : [21204992, 21205248)     256 B zeros
#define XB_OFF 0
#define WB_OFF 20975616
#define ZP_OFF 21204992

// w[o][c][k] f32 -> wb[k][o][c] bf16 (k<7 only); also zero the zero-page.
__global__ void wprep_kernel(const float* __restrict__ w, unsigned short* __restrict__ wb,
                             unsigned short* __restrict__ zp) {
    int i = blockIdx.x * 256 + threadIdx.x;
    if (i < 128 && blockIdx.x == 0) zp[i] = 0;
    if (i >= KS_ACT * CC * CC) return;
    int k = i >> 14;                  // /16384
    int r = i & 16383;
    int o = r >> 7;
    int c = r & 127;
    wb[i] = (unsigned short)f2bf(w[(o * CC + c) * 9 + k]);
}

// x f32 -> xb bf16, 8 elems/thread
__global__ void xprep_kernel(const float* __restrict__ x, unsigned short* __restrict__ xb, int n8) {
    int i = blockIdx.x * 256 + threadIdx.x;
    if (i >= n8) return;
    const float4* s = (const float4*)(x + (size_t)i * 8);
    float4 a = s[0], b = s[1];
    uint4 p;
    p.x = f2bf(a.x) | (f2bf(a.y) << 16);
    p.y = f2bf(a.z) | (f2bf(a.w) << 16);
    p.z = f2bf(b.x) | (f2bf(b.y) << 16);
    p.w = f2bf(b.z) | (f2bf(b.w) << 16);
    *(uint4*)(xb + (size_t)i * 8) = p;
}

__global__ __launch_bounds__(256, 3)
void icoconv_kernel(const unsigned short* __restrict__ xb,
                    const unsigned short* __restrict__ wb,
                    const unsigned short* __restrict__ zp,
                    const float* __restrict__ bias,
                    const int* __restrict__ nidx,
                    const float* __restrict__ nmask,
                    float* __restrict__ out) {
    __shared__ __align__(16) unsigned short As[BM * CC];   // 32 KB, XOR-swizzled rows

    const int tid  = threadIdx.x;
    const int lane = tid & 63;
    const int wid  = tid >> 6;
    const int bb   = blockIdx.x / VT_PER_B;
    const int vt   = blockIdx.x - bb * VT_PER_B;
    const int vbase = vt * BM;

    const int sr = tid >> 1;          // staging row 0..127
    const int sh = tid & 1;           // which 128-B half of the row
    const int v  = vbase + sr;
    const bool valid = v < V_CNT;

    // hoisted ring indices + mask bits for this thread's staging row
    int gidx[KS_ACT];
    unsigned mbits = 0;
    #pragma unroll
    for (int k = 0; k < KS_ACT; ++k) {
        int g = 0; float mk = 0.f;
        if (valid) { g = nidx[v * 9 + k]; mk = nmask[v * 9 + k]; }
        gidx[k] = g;
        mbits |= (mk != 0.f ? 1u : 0u) << k;
    }
    const unsigned short* xbatch = xb + (size_t)bb * V_CNT * CC;

    const int wave_m = wid >> 1;      // 0..1
    const int wave_n = wid & 1;       // 0..1

    f32x4 acc[4][4];
    #pragma unroll
    for (int i = 0; i < 4; ++i)
        #pragma unroll
        for (int j = 0; j < 4; ++j)
            acc[i][j] = f32x4{0.f, 0.f, 0.f, 0.f};

    // B fragment lane base: Wb[k][o][c], o = wave_n*64 + ni*16 + (lane&15), c = kk*32 + (lane>>4)*8
    const unsigned short* wlane = wb + (wave_n * 64 + (lane & 15)) * CC + ((lane >> 4) << 3);

    // A staging write base (swizzled) and read swizzle
    char* awr = (char*)As + sr * 256;
    const int swz = (sr & 7) << 4;

    // prologue: prefetch slot 0 into registers (8 x dwordx4 = 128 B)
    uint4 pf[8];
    {
        const unsigned short* s = ((mbits & 1u) ? (xbatch + (size_t)gidx[0] * CC) : zp) + sh * 64;
        #pragma unroll
        for (int q = 0; q < 8; ++q) pf[q] = *(const uint4*)(s + q * 8);
    }

    for (int ks = 0; ks < KS_ACT; ++ks) {
        __syncthreads();              // all waves done reading As (previous slot)
        // write current slot's rows to LDS (swizzled)
        #pragma unroll
        for (int q = 0; q < 8; ++q) {
            int w = sh * 8 + q;
            *(uint4*)(awr + ((w * 16) ^ swz)) = pf[q];
        }
        // issue next slot's gather now; lands during this slot's compute (T14)
        if (ks + 1 < KS_ACT) {
            const unsigned short* s =
                (((mbits >> (ks + 1)) & 1u) ? (xbatch + (size_t)gidx[ks + 1] * CC) : zp) + sh * 64;
            #pragma unroll
            for (int q = 0; q < 8; ++q) pf[q] = *(const uint4*)(s + q * 8);
        }
        __syncthreads();              // As ready (syncthreads waits lgkmcnt)

        const unsigned short* wks = wlane + ks * (CC * CC);
        #pragma unroll
        for (int kk = 0; kk < 4; ++kk) {
            short8 bfr[4], af[4];
            #pragma unroll
            for (int ni = 0; ni < 4; ++ni)
                bfr[ni] = *(const short8*)(wks + ni * 16 * CC + kk * 32);
            #pragma unroll
            for (int mi = 0; mi < 4; ++mi) {
                int row = wave_m * 64 + mi * 16 + (lane & 15);
                af[mi] = *(const short8*)((const char*)As + row * 256 +
                          ((kk * 64 + ((lane >> 4) << 4)) ^ ((row & 7) << 4)));
            }
            #pragma unroll
            for (int mi = 0; mi < 4; ++mi)
                #pragma unroll
                for (int ni = 0; ni < 4; ++ni)
                    acc[mi][ni] = __builtin_amdgcn_mfma_f32_16x16x32_bf16(af[mi], bfr[ni], acc[mi][ni], 0, 0, 0);
        }
    }

    // epilogue: D row=(lane>>4)*4+j, col=lane&15 (m89-verified)
    #pragma unroll
    for (int ni = 0; ni < 4; ++ni) {
        int col = wave_n * 64 + ni * 16 + (lane & 15);
        float bv = bias[col];
        #pragma unroll
        for (int mi = 0; mi < 4; ++mi) {
            int row0 = wave_m * 64 + mi * 16 + ((lane >> 4) << 2);
            #pragma unroll
            for (int j = 0; j < 4; ++j) {
                int vv = vbase + row0 + j;
                if (vv < V_CNT)
                    out[((size_t)bb * V_CNT + vv) * CC + col] = acc[mi][ni][j] + bv;
            }
        }
    }
}

extern "C" void kernel_launch(void* const* d_in, const int* in_sizes, int n_in,
                              void* d_out, int out_size, void* d_ws, size_t ws_size,
                              hipStream_t stream) {
    const float* x     = (const float*)d_in[0];
    const float* w     = (const float*)d_in[1];
    const float* bias  = (const float*)d_in[2];
    const int*   nidx  = (const int*)d_in[3];
    const float* nmask = (const float*)d_in[4];
    float* out = (float*)d_out;

    unsigned short* xb = (unsigned short*)((char*)d_ws + XB_OFF);
    unsigned short* wb = (unsigned short*)((char*)d_ws + WB_OFF);
    unsigned short* zp = (unsigned short*)((char*)d_ws + ZP_OFF);

    wprep_kernel<<<(KS_ACT * CC * CC + 255) / 256, 256, 0, stream>>>(w, wb, zp);

    int n8 = BATCH * V_CNT * CC / 8;    // 1310976
    xprep_kernel<<<(n8 + 255) / 256, 256, 0, stream>>>(x, xb, n8);

    icoconv_kernel<<<BATCH * VT_PER_B, 256, 0, stream>>>(xb, wb, zp, bias, nidx, nmask, out);
}

// Round 5
// 197.700 us; speedup vs baseline: 1.0234x; 1.0234x over previous
//
#include <hip/hip_runtime.h>
#include <hip/hip_bf16.h>

// IcosahedronConv2d: out[b,v,o] = sum_{k,c} x[b, idx[v,k], c] * mask[v,k] * w[o,c,k] + bias[o]
// B=8, V=10242, C=128, 9 k-slots (7,8 always masked; 6 masked only for 12 pentagons).
// v4: v3 + coalesced epilogue (acc -> LDS transpose -> float4 full-line stores).

#define V_CNT    10242
#define CC       128
#define KS_ACT   7
#define BM       128
#define VT_PER_B 81          // ceil(10242/128)
#define BATCH    8

typedef short short8 __attribute__((ext_vector_type(8)));
typedef float f32x4  __attribute__((ext_vector_type(4)));

__device__ __forceinline__ unsigned f2bf(float f) {
    unsigned u = __float_as_uint(f);
    u += 0x7fffu + ((u >> 16) & 1u);      // RNE
    return u >> 16;
}

// ws layout (bytes):
//   xb : [0, 20975616)            8*10242*128 bf16
//   wb : [20975616, 21204992)     7*128*128 bf16   Wb[k][o][c]
//   zp : [21204992, 21205248)     256 B zeros
#define XB_OFF 0
#define WB_OFF 20975616
#define ZP_OFF 21204992

// w[o][c][k] f32 -> wb[k][o][c] bf16 (k<7 only); also zero the zero-page.
__global__ void wprep_kernel(const float* __restrict__ w, unsigned short* __restrict__ wb,
                             unsigned short* __restrict__ zp) {
    int i = blockIdx.x * 256 + threadIdx.x;
    if (i < 128 && blockIdx.x == 0) zp[i] = 0;
    if (i >= KS_ACT * CC * CC) return;
    int k = i >> 14;                  // /16384
    int r = i & 16383;
    int o = r >> 7;
    int c = r & 127;
    wb[i] = (unsigned short)f2bf(w[(o * CC + c) * 9 + k]);
}

// x f32 -> xb bf16, 8 elems/thread
__global__ void xprep_kernel(const float* __restrict__ x, unsigned short* __restrict__ xb, int n8) {
    int i = blockIdx.x * 256 + threadIdx.x;
    if (i >= n8) return;
    const float4* s = (const float4*)(x + (size_t)i * 8);
    float4 a = s[0], b = s[1];
    uint4 p;
    p.x = f2bf(a.x) | (f2bf(a.y) << 16);
    p.y = f2bf(a.z) | (f2bf(a.w) << 16);
    p.z = f2bf(b.x) | (f2bf(b.y) << 16);
    p.w = f2bf(b.z) | (f2bf(b.w) << 16);
    *(uint4*)(xb + (size_t)i * 8) = p;
}

__global__ __launch_bounds__(256, 3)
void icoconv_kernel(const unsigned short* __restrict__ xb,
                    const unsigned short* __restrict__ wb,
                    const unsigned short* __restrict__ zp,
                    const float* __restrict__ bias,
                    const int* __restrict__ nidx,
                    const float* __restrict__ nmask,
                    float* __restrict__ out) {
    // union: As [128][128] bf16 (swizzled) for K-loop; Os [64][132] f32 for epilogue
    __shared__ __align__(16) char smem[64 * 132 * 4];   // 33792 B
    unsigned short* As = (unsigned short*)smem;
    float* Os = (float*)smem;

    const int tid  = threadIdx.x;
    const int lane = tid & 63;
    const int wid  = tid >> 6;
    const int bb   = blockIdx.x / VT_PER_B;
    const int vt   = blockIdx.x - bb * VT_PER_B;
    const int vbase = vt * BM;

    const int sr = tid >> 1;          // staging row 0..127
    const int sh = tid & 1;           // which 128-B half of the row
    const int v  = vbase + sr;
    const bool valid = v < V_CNT;

    // hoisted ring indices + mask bits for this thread's staging row
    int gidx[KS_ACT];
    unsigned mbits = 0;
    #pragma unroll
    for (int k = 0; k < KS_ACT; ++k) {
        int g = 0; float mk = 0.f;
        if (valid) { g = nidx[v * 9 + k]; mk = nmask[v * 9 + k]; }
        gidx[k] = g;
        mbits |= (mk != 0.f ? 1u : 0u) << k;
    }
    const unsigned short* xbatch = xb + (size_t)bb * V_CNT * CC;

    const int wave_m = wid >> 1;      // 0..1
    const int wave_n = wid & 1;       // 0..1

    f32x4 acc[4][4];
    #pragma unroll
    for (int i = 0; i < 4; ++i)
        #pragma unroll
        for (int j = 0; j < 4; ++j)
            acc[i][j] = f32x4{0.f, 0.f, 0.f, 0.f};

    // B fragment lane base: Wb[k][o][c], o = wave_n*64 + ni*16 + (lane&15), c = kk*32 + (lane>>4)*8
    const unsigned short* wlane = wb + (wave_n * 64 + (lane & 15)) * CC + ((lane >> 4) << 3);

    // A staging write base (swizzled) and read swizzle
    char* awr = (char*)As + sr * 256;
    const int swz = (sr & 7) << 4;

    // prologue: prefetch slot 0 into registers (8 x dwordx4 = 128 B)
    uint4 pf[8];
    {
        const unsigned short* s = ((mbits & 1u) ? (xbatch + (size_t)gidx[0] * CC) : zp) + sh * 64;
        #pragma unroll
        for (int q = 0; q < 8; ++q) pf[q] = *(const uint4*)(s + q * 8);
    }

    for (int ks = 0; ks < KS_ACT; ++ks) {
        __syncthreads();              // all waves done reading As (previous slot)
        #pragma unroll
        for (int q = 0; q < 8; ++q) {
            int w = sh * 8 + q;
            *(uint4*)(awr + ((w * 16) ^ swz)) = pf[q];
        }
        // issue next slot's gather now; lands during this slot's compute (T14)
        if (ks + 1 < KS_ACT) {
            const unsigned short* s =
                (((mbits >> (ks + 1)) & 1u) ? (xbatch + (size_t)gidx[ks + 1] * CC) : zp) + sh * 64;
            #pragma unroll
            for (int q = 0; q < 8; ++q) pf[q] = *(const uint4*)(s + q * 8);
        }
        __syncthreads();              // As ready

        const unsigned short* wks = wlane + ks * (CC * CC);
        #pragma unroll
        for (int kk = 0; kk < 4; ++kk) {
            short8 bfr[4], af[4];
            #pragma unroll
            for (int ni = 0; ni < 4; ++ni)
                bfr[ni] = *(const short8*)(wks + ni * 16 * CC + kk * 32);
            #pragma unroll
            for (int mi = 0; mi < 4; ++mi) {
                int row = wave_m * 64 + mi * 16 + (lane & 15);
                af[mi] = *(const short8*)((const char*)As + row * 256 +
                          ((kk * 64 + ((lane >> 4) << 4)) ^ ((row & 7) << 4)));
            }
            #pragma unroll
            for (int mi = 0; mi < 4; ++mi)
                #pragma unroll
                for (int ni = 0; ni < 4; ++ni)
                    acc[mi][ni] = __builtin_amdgcn_mfma_f32_16x16x32_bf16(af[mi], bfr[ni], acc[mi][ni], 0, 0, 0);
        }
    }

    // ---- epilogue v4: acc -> LDS (64x132 f32, padded) -> coalesced float4 stores ----
    __syncthreads();                  // last slot's As reads complete before aliasing as Os
    const int r8 = tid >> 5;          // 0..7
    const int c4 = (tid & 31) << 2;   // 0,4,...,124
    float4 bv = *(const float4*)(bias + c4);

    #pragma unroll
    for (int pass = 0; pass < 2; ++pass) {
        if (wave_m == pass) {
            #pragma unroll
            for (int mi = 0; mi < 4; ++mi) {
                int lrow = mi * 16 + ((lane >> 4) << 2);
                #pragma unroll
                for (int ni = 0; ni < 4; ++ni) {
                    int lcol = wave_n * 64 + ni * 16 + (lane & 15);
                    #pragma unroll
                    for (int j = 0; j < 4; ++j)
                        Os[(lrow + j) * 132 + lcol] = acc[mi][ni][j];
                }
            }
        }
        __syncthreads();
        #pragma unroll
        for (int it = 0; it < 8; ++it) {
            int r = it * 8 + r8;
            int vv = vbase + pass * 64 + r;
            if (vv < V_CNT) {
                float4 val = *(const float4*)(Os + r * 132 + c4);
                val.x += bv.x; val.y += bv.y; val.z += bv.z; val.w += bv.w;
                *(float4*)(out + ((size_t)bb * V_CNT + vv) * CC + c4) = val;
            }
        }
        __syncthreads();              // pass-0 reads done before pass-1 overwrites
    }
}

extern "C" void kernel_launch(void* const* d_in, const int* in_sizes, int n_in,
                              void* d_out, int out_size, void* d_ws, size_t ws_size,
                              hipStream_t stream) {
    const float* x     = (const float*)d_in[0];
    const float* w     = (const float*)d_in[1];
    const float* bias  = (const float*)d_in[2];
    const int*   nidx  = (const int*)d_in[3];
    const float* nmask = (const float*)d_in[4];
    float* out = (float*)d_out;

    unsigned short* xb = (unsigned short*)((char*)d_ws + XB_OFF);
    unsigned short* wb = (unsigned short*)((char*)d_ws + WB_OFF);
    unsigned short* zp = (unsigned short*)((char*)d_ws + ZP_OFF);

    wprep_kernel<<<(KS_ACT * CC * CC + 255) / 256, 256, 0, stream>>>(w, wb, zp);

    int n8 = BATCH * V_CNT * CC / 8;    // 1310976
    xprep_kernel<<<(n8 + 255) / 256, 256, 0, stream>>>(x, xb, n8);

    icoconv_kernel<<<BATCH * VT_PER_B, 256, 0, stream>>>(xb, wb, zp, bias, nidx, nmask, out);
}

// Round 6
// 193.675 us; speedup vs baseline: 1.0447x; 1.0208x over previous
//
#include <hip/hip_runtime.h>
#include <hip/hip_bf16.h>

// IcosahedronConv2d: out[b,v,o] = sum_{k,c} x[b, idx[v,k], c] * mask[v,k] * w[o,c,k] + bias[o]
// B=8, V=10242, C=128. v5: BM=64 (grid 1288, TLP), LDS-dbuf A + 1 barrier/slot,
// fully static-unrolled 7-slot pipeline, nt stores, fused prep kernel.

#define V_CNT    10242
#define CC       128
#define KS_ACT   7
#define BM       64
#define VT_PER_B 161         // ceil(10242/64)
#define BATCH    8

typedef short short8 __attribute__((ext_vector_type(8)));
typedef float f32x4  __attribute__((ext_vector_type(4)));

__device__ __forceinline__ unsigned f2bf(float f) {
    unsigned u = __float_as_uint(f);
    u += 0x7fffu + ((u >> 16) & 1u);      // RNE
    return u >> 16;
}

// ws layout (bytes):
//   xb : [0, 20975616)            8*10242*128 bf16
//   wb : [20975616, 21204992)     7*128*128 bf16   Wb[k][o][c]
//   zp : [21204992, 21205248)     256 B zeros
#define XB_OFF 0
#define WB_OFF 20975616
#define ZP_OFF 21204992

#define XB_BLOCKS 5121       // 8*10242*128/8 / 256
#define WB_BLOCKS 448        // 7*128*128 / 256

// fused prep: xb bf16 cast (8 elem/thread) + wb transform (1 elem/thread) + zero-page
__global__ void prep_kernel(const float* __restrict__ x, const float* __restrict__ w,
                            unsigned short* __restrict__ xb, unsigned short* __restrict__ wb,
                            unsigned short* __restrict__ zp, int n8) {
    int b = blockIdx.x;
    if (b < XB_BLOCKS) {
        int i = b * 256 + threadIdx.x;
        if (i < n8) {
            const float4* s = (const float4*)(x + (size_t)i * 8);
            float4 a = s[0], c = s[1];
            uint4 p;
            p.x = f2bf(a.x) | (f2bf(a.y) << 16);
            p.y = f2bf(a.z) | (f2bf(a.w) << 16);
            p.z = f2bf(c.x) | (f2bf(c.y) << 16);
            p.w = f2bf(c.z) | (f2bf(c.w) << 16);
            *(uint4*)(xb + (size_t)i * 8) = p;
        }
    } else if (b < XB_BLOCKS + WB_BLOCKS) {
        int i = (b - XB_BLOCKS) * 256 + threadIdx.x;   // < 114688
        int k = i >> 14;
        int r = i & 16383;
        int o = r >> 7;
        int c = r & 127;
        wb[i] = (unsigned short)f2bf(w[(o * CC + c) * 9 + k]);
    } else {
        if (threadIdx.x < 128) zp[threadIdx.x] = 0;
    }
}

__global__ __launch_bounds__(256, 3)
void icoconv_kernel(const unsigned short* __restrict__ xb,
                    const unsigned short* __restrict__ wb,
                    const unsigned short* __restrict__ zp,
                    const float* __restrict__ bias,
                    const int* __restrict__ nidx,
                    const float* __restrict__ nmask,
                    float* __restrict__ out) {
    // union: As0/As1 [64][128] bf16 ping-pong (2x16 KB) ; Os [64][132] f32 epilogue
    __shared__ __align__(16) char smem[64 * 132 * 4];   // 33792 B
    unsigned short* As0 = (unsigned short*)smem;
    unsigned short* As1 = (unsigned short*)(smem + 16384);
    float* Os = (float*)smem;

    const int tid  = threadIdx.x;
    const int lane = tid & 63;
    const int wid  = tid >> 6;            // 0..3 : 32-col strip of N
    const int bb   = blockIdx.x / VT_PER_B;
    const int vt   = blockIdx.x - bb * VT_PER_B;
    const int vbase = vt * BM;

    const int sr = tid >> 2;              // staging row 0..63
    const int sh = tid & 3;               // 64-B quarter of the row
    const int v  = vbase + sr;
    const bool valid = v < V_CNT;

    int gidx[KS_ACT];
    unsigned mbits = 0;
    #pragma unroll
    for (int k = 0; k < KS_ACT; ++k) {
        int g = 0; float mk = 0.f;
        if (valid) { g = nidx[v * 9 + k]; mk = nmask[v * 9 + k]; }
        gidx[k] = g;
        mbits |= (mk != 0.f ? 1u : 0u) << k;
    }
    const unsigned short* xbatch = xb + (size_t)bb * V_CNT * CC;

    f32x4 acc[4][2];
    #pragma unroll
    for (int i = 0; i < 4; ++i)
        #pragma unroll
        for (int j = 0; j < 2; ++j)
            acc[i][j] = f32x4{0.f, 0.f, 0.f, 0.f};

    // B lane base: Wb[k][o][c], o = wid*32 + ni*16 + (lane&15), c = kk*32 + (lane>>4)*8
    const unsigned short* wlane = wb + (wid * 32 + (lane & 15)) * CC + ((lane >> 4) << 3);

    const int swz  = (sr & 7) << 4;       // staging-row swizzle
    const int hi16 = (lane >> 4) << 4;    // fragment k-group byte offset

    // prologue: gather s0, write buf0, gather s1
    uint4 pf[4];
    {
        const unsigned short* s = ((mbits & 1u) ? (xbatch + (size_t)gidx[0] * CC) : zp) + sh * 32;
        #pragma unroll
        for (int q = 0; q < 4; ++q) pf[q] = *(const uint4*)(s + q * 8);
    }
    {
        char* wdst = (char*)As0 + sr * 256;
        #pragma unroll
        for (int q = 0; q < 4; ++q)
            *(uint4*)(wdst + ((sh * 64 + q * 16) ^ swz)) = pf[q];
    }
    {
        const unsigned short* s = (((mbits >> 1) & 1u) ? (xbatch + (size_t)gidx[1] * CC) : zp) + sh * 32;
        #pragma unroll
        for (int q = 0; q < 4; ++q) pf[q] = *(const uint4*)(s + q * 8);
    }
    __syncthreads();

    // main: fully unrolled, 1 barrier per slot, A dbuf, gather 1 slot ahead
    #pragma unroll
    for (int t = 0; t < KS_ACT; ++t) {
        const unsigned short* bcur = (t & 1) ? As1 : As0;
        unsigned short*       bnxt = (t & 1) ? As0 : As1;

        if (t < KS_ACT - 1) {            // write s(t+1) into the other buffer
            char* wdst = (char*)bnxt + sr * 256;
            #pragma unroll
            for (int q = 0; q < 4; ++q)
                *(uint4*)(wdst + ((sh * 64 + q * 16) ^ swz)) = pf[q];
        }

        // B fragments for this slot (L2-hot, consumed below)
        const unsigned short* wks = wlane + t * (CC * CC);
        short8 bfr[4][2];
        #pragma unroll
        for (int kk = 0; kk < 4; ++kk)
            #pragma unroll
            for (int ni = 0; ni < 2; ++ni)
                bfr[kk][ni] = *(const short8*)(wks + ni * 16 * CC + kk * 32);

        if (t < KS_ACT - 2) {            // gather s(t+2); lands during this slot's compute
            const int k2 = t + 2;
            const unsigned short* s =
                (((mbits >> k2) & 1u) ? (xbatch + (size_t)gidx[k2] * CC) : zp) + sh * 32;
            #pragma unroll
            for (int q = 0; q < 4; ++q) pf[q] = *(const uint4*)(s + q * 8);
        }

        #pragma unroll
        for (int kk = 0; kk < 4; ++kk) {
            short8 af[4];
            #pragma unroll
            for (int mi = 0; mi < 4; ++mi) {
                int row = mi * 16 + (lane & 15);
                af[mi] = *(const short8*)((const char*)bcur + row * 256 +
                          ((kk * 64 + hi16) ^ ((row & 7) << 4)));
            }
            #pragma unroll
            for (int mi = 0; mi < 4; ++mi)
                #pragma unroll
                for (int ni = 0; ni < 2; ++ni)
                    acc[mi][ni] = __builtin_amdgcn_mfma_f32_16x16x32_bf16(af[mi], bfr[kk][ni], acc[mi][ni], 0, 0, 0);
        }

        if (t < KS_ACT - 1) __syncthreads();
    }

    // epilogue: acc -> Os (64x132 f32) -> coalesced nt float4 stores
    __syncthreads();                     // all waves done reading As before aliasing as Os
    #pragma unroll
    for (int mi = 0; mi < 4; ++mi) {
        int lrow = mi * 16 + ((lane >> 4) << 2);
        #pragma unroll
        for (int ni = 0; ni < 2; ++ni) {
            int lcol = wid * 32 + ni * 16 + (lane & 15);
            #pragma unroll
            for (int j = 0; j < 4; ++j)
                Os[(lrow + j) * 132 + lcol] = acc[mi][ni][j];
        }
    }
    __syncthreads();

    {
        const int r  = tid >> 2;          // 0..63
        const int cb = (tid & 3) << 5;    // 0,32,64,96
        const int vv = vbase + r;
        if (vv < V_CNT) {
            float* op = out + ((size_t)bb * V_CNT + vv) * CC + cb;
            #pragma unroll
            for (int q = 0; q < 8; ++q) {
                f32x4 val = *(const f32x4*)(Os + r * 132 + cb + q * 4);
                f32x4 bv  = *(const f32x4*)(bias + cb + q * 4);
                val = val + bv;
                __builtin_nontemporal_store(val, (f32x4*)(op + q * 4));
            }
        }
    }
}

extern "C" void kernel_launch(void* const* d_in, const int* in_sizes, int n_in,
                              void* d_out, int out_size, void* d_ws, size_t ws_size,
                              hipStream_t stream) {
    const float* x     = (const float*)d_in[0];
    const float* w     = (const float*)d_in[1];
    const float* bias  = (const float*)d_in[2];
    const int*   nidx  = (const int*)d_in[3];
    const float* nmask = (const float*)d_in[4];
    float* out = (float*)d_out;

    unsigned short* xb = (unsigned short*)((char*)d_ws + XB_OFF);
    unsigned short* wb = (unsigned short*)((char*)d_ws + WB_OFF);
    unsigned short* zp = (unsigned short*)((char*)d_ws + ZP_OFF);

    int n8 = BATCH * V_CNT * CC / 8;    // 1310976
    prep_kernel<<<XB_BLOCKS + WB_BLOCKS + 1, 256, 0, stream>>>(x, w, xb, wb, zp, n8);

    icoconv_kernel<<<BATCH * VT_PER_B, 256, 0, stream>>>(xb, wb, zp, bias, nidx, nmask, out);
}